// Round 7
// baseline (282.443 us; speedup 1.0000x reference)
//
#include <hip/hip_runtime.h>

// g2[b,c,h,w] = sum_d cost[b,d,h,w] * h1[b,c,h,w+d]   (w+d < W, else 0)
// B=4 C=32 H=256 W=512 D=48, fp32.
//
// v6 (3rd submit; rounds 5-6 failed on container acquire — audited: no
// OOB, no hang potential, no graph-capture violation; infra flake):
// NO LDS. v3/v5 both hit the same ~110us wall; counter arithmetic shows
// the LDS pipe at ~100% (23.6k wave-ops/CU x 8cy + 85k conflict cy ~=
// the whole 271k-cycle dispatch), dominated by h1 STAGING WRITES -- and
// h1 has zero cross-wave reuse (each channel is owned by one wave), so
// LDS was pure overhead: every byte crossed the 128 B/cy LDS pipe twice
// for no sharing.
// Fix: slide the h1 window directly from global memory. Per channel per
// group: one coalesced global_load_dwordx4 (64 lanes x 16B contiguous)
// into the register window. Tail mask is cheap: quads are 4-aligned and
// W%4==0, so a quad is fully in- or out-of-range -> clamp addr in-row
// + 1 cmp + 4 cndmask.
//   - NT=256, 4 waves x 2 channels = 8 channels/block;
//     grid = B*H*2*(32/8) = 8192. No barrier anywhere.
//   - occupancy: no LDS limit -> 8 blocks/CU (thread cap) = 32 waves.
//   - live regs: win 16 + acc 8 + cv 16 + ptrs ~10 ~= 55 < 64 cap.

#define BB 4
#define CC 32
#define HH 256
#define WW 512
#define DDISP 48
#define HW (HH * WW)     // 131072
#define TW 256
#define NT 256

// masked h1 quad load: quad fully in-range iff wq < W (quads 4-aligned,
// W%4==0 -> no partial quads). Clamp keeps the address inside the row.
__device__ __forceinline__ void ldh(const float* __restrict__ row, int wq,
                                    float* __restrict__ dst)
{
    int wc = wq > (WW - 4) ? (WW - 4) : wq;
    float4 t = *(const float4*)(row + wc);
    bool ok = wq < WW;
    dst[0] = ok ? t.x : 0.f;
    dst[1] = ok ? t.y : 0.f;
    dst[2] = ok ? t.z : 0.f;
    dst[3] = ok ? t.w : 0.f;
}

__global__ __launch_bounds__(NT, 4)
void dense_warp_kernel(const float* __restrict__ h1,
                       const float* __restrict__ cost,
                       float* __restrict__ out)
{
    const int blk    = blockIdx.x;
    const int wside  = blk & 1;
    const int h      = (blk >> 1) & (HH - 1);
    const int cgrp   = (blk >> 9) & 3;
    const int b      = blk >> 11;
    const int wstart = wside * TW;

    const int lane = threadIdx.x & 63;
    const int wid  = threadIdx.x >> 6;     // 0..3
    const int c0   = (cgrp << 3) + (wid << 1);   // 2 channels per wave
    const int w0   = lane << 2;
    const int wq0  = wstart + w0;          // this lane's first output w

    const float* r0 = h1 + (((size_t)b * CC + c0    ) * HH + h) * WW;
    const float* r1 = h1 + (((size_t)b * CC + c0 + 1) * HH + h) * WW;

    float acc0[4] = {0.f, 0.f, 0.f, 0.f};
    float acc1[4] = {0.f, 0.f, 0.f, 0.f};

    // win[slot*4+k]: circular 2-quad window. Invariant at start of group g:
    // slot (g&1) = h1 quad at wq0+4g, slot ((g+1)&1) = quad at wq0+4g+4.
    float win0[8], win1[8];
    ldh(r0, wq0,     &win0[0]);  ldh(r0, wq0 + 4, &win0[4]);
    ldh(r1, wq0,     &win1[0]);  ldh(r1, wq0 + 4, &win1[4]);

    const float* cp = cost + ((size_t)b * DDISP * HH + h) * WW + wq0;

    // Group g covers d = 4g..4g+3; output j needs operand wq0+4g+(dd+j),
    // dd+j in 0..6 -> the 2-quad window [4g, 4g+7].
#pragma unroll
    for (int g = 0; g < 12; ++g) {
        const int P = g & 1;   // static after unroll
        float cv[4][4];
#pragma unroll
        for (int dd = 0; dd < 4; ++dd) {
            float4 t = *(const float4*)(cp + (size_t)(4 * g + dd) * HW);
            cv[dd][0] = t.x; cv[dd][1] = t.y; cv[dd][2] = t.z; cv[dd][3] = t.w;
        }
#pragma unroll
        for (int dd = 0; dd < 4; ++dd)
#pragma unroll
            for (int j = 0; j < 4; ++j) {
                const int o    = dd + j;              // 0..6
                const int slot = (P + (o >> 2)) & 1;
                acc0[j] += cv[dd][j] * win0[slot * 4 + (o & 3)];
                acc1[j] += cv[dd][j] * win1[slot * 4 + (o & 3)];
            }
        // slide: overwrite the now-dead slot P with quad g+2 (wq0+4g+8),
        // loaded straight into the window registers (used next group ->
        // one group of latency slack + 32-wave TLP).
        ldh(r0, wq0 + 4 * g + 8, &win0[P * 4]);
        ldh(r1, wq0 + 4 * g + 8, &win1[P * 4]);
    }

    float* o0 = out + (((size_t)b * CC + c0    ) * HH + h) * WW + wq0;
    float* o1 = out + (((size_t)b * CC + c0 + 1) * HH + h) * WW + wq0;
    *(float4*)o0 = make_float4(acc0[0], acc0[1], acc0[2], acc0[3]);
    *(float4*)o1 = make_float4(acc1[0], acc1[1], acc1[2], acc1[3]);
}

extern "C" void kernel_launch(void* const* d_in, const int* in_sizes, int n_in,
                              void* d_out, int out_size, void* d_ws, size_t ws_size,
                              hipStream_t stream) {
    const float* h1   = (const float*)d_in[0];
    const float* cost = (const float*)d_in[1];
    float* out        = (float*)d_out;
    dim3 grid(BB * HH * 2 * 4);   // (b, cgrp, h, w-half) = 8192
    dense_warp_kernel<<<grid, NT, 0, stream>>>(h1, cost, out);
}